// Round 1
// baseline (286.406 us; speedup 1.0000x reference)
//
#include <hip/hip_runtime.h>

#define NB 8
#define NS 2048
#define NH 768
#define NPOS (NB*NS)

typedef short short8 __attribute__((ext_vector_type(8)));
typedef float floatx4 __attribute__((ext_vector_type(4)));

// pack bf16-truncations of two fp32 into one dword: low short=hi(b0), high short=hi(b1)
__device__ __forceinline__ unsigned pack_bf16(unsigned b0, unsigned b1) {
  return __builtin_amdgcn_perm(b1, b0, 0x07060302u);
}

// async global->LDS, 16B per lane; LDS dest must be wave-uniform base + lane*16
#define GLOAD_LDS16(gp, lp) __builtin_amdgcn_global_load_lds( \
  (const __attribute__((address_space(1))) unsigned int*)(gp), \
  (__attribute__((address_space(3))) unsigned int*)(lp), 16, 0, 0)

// ---------------- Kernel Epre: pre-tile E into swizzled bf16 hi/lo tiles ----------------
// Tile (b, hb, tc) = [192 h][32 t], 12288 shorts (24 KB): hi image [0,6144),
// lo image [6144,12288); within each: off = h2*32 + ((q2^((h2>>1)&3))*8).
// Block (0,0,0) threads 0..15 additionally build V = U*diag((-i)^popc) (tiny).
__global__ __launch_bounds__(384) void epre_kernel(
    const float* __restrict__ E, const float* __restrict__ wts,
    float* __restrict__ Vre, float* __restrict__ Vim,
    unsigned short* __restrict__ ET) {
  int tc = blockIdx.x, hb = blockIdx.y, b = blockIdx.z;
  int tid = threadIdx.x;

  if (tc == 0 && hb == 0 && b == 0 && tid < 16) {
    int j = tid;
    float ar[16], ai[16];
#pragma unroll
    for (int i = 0; i < 16; i++) { ar[i] = (i == j) ? 1.f : 0.f; ai[i] = 0.f; }
#pragma unroll
    for (int l = 0; l < 2; l++) {
#pragma unroll
      for (int q = 0; q < 4; q++) {
        float phi = wts[(l*4+q)*3+0];
        float th  = wts[(l*4+q)*3+1];
        float om  = wts[(l*4+q)*3+2];
        float ct = cosf(0.5f*th), st = sinf(0.5f*th);
        float sm = 0.5f*(phi+om), df = 0.5f*(phi-om);
        float cs = cosf(sm), ss = sinf(sm), cd = cosf(df), sd = sinf(df);
        float Ar =  cs*ct, Ai = -ss*ct;
        float Br = -cd*st, Bi = -sd*st;
        float Cr =  cd*st, Ci = -sd*st;
        float Dr =  cs*ct, Di =  ss*ct;
        int pb = 1 << (3-q);
#pragma unroll
        for (int b0 = 0; b0 < 16; b0++) {
          if (b0 & pb) continue;
          int b1 = b0 | pb;
          float xr = ar[b0], xi = ai[b0], yr = ar[b1], yi = ai[b1];
          ar[b0] = Ar*xr - Ai*xi + Br*yr - Bi*yi;
          ai[b0] = Ar*xi + Ai*xr + Br*yi + Bi*yr;
          ar[b1] = Cr*xr - Ci*xi + Dr*yr - Di*yi;
          ai[b1] = Cr*xi + Ci*xr + Dr*yi + Di*yr;
        }
      }
      const int r = (l == 0) ? 1 : 2;
#pragma unroll
      for (int i2 = 0; i2 < 4; i2++) {
        int cb = 1 << (3-i2);
        int tb = 1 << (3-((i2+r)&3));
#pragma unroll
        for (int b0 = 0; b0 < 16; b0++) {
          if ((b0 & cb) && !(b0 & tb)) {
            int b1 = b0 | tb;
            float tr = ar[b0], ti = ai[b0];
            ar[b0] = ar[b1]; ai[b0] = ai[b1];
            ar[b1] = tr;     ai[b1] = ti;
          }
        }
      }
    }
    int pc = __popc((unsigned)j) & 3;
#pragma unroll
    for (int i = 0; i < 16; i++) {
      float vr = ar[i], vi = ai[i], orr, oi;
      if      (pc == 0) { orr =  vr; oi =  vi; }
      else if (pc == 1) { orr =  vi; oi = -vr; }
      else if (pc == 2) { orr = -vr; oi = -vi; }
      else              { orr = -vi; oi =  vr; }
      Vre[i*16+j] = orr;
      Vim[i*16+j] = oi;
    }
  }

  size_t tbase = ((size_t)((b*4 + hb)*64 + tc)) * 12288;
  const float* Eb = E + (size_t)b*NS*NH + (size_t)tc*32*NH + hb*192;
#pragma unroll
  for (int u = 0; u < 2; u++) {
    int unit = tid + 384*u;          // 0..767
    int q2 = unit / 192, h2 = unit % 192;
    unsigned hi4[4], lo4[4];
#pragma unroll
    for (int jp = 0; jp < 4; jp++) {
      float ea = Eb[(size_t)(q2*8 + 2*jp    )*NH + h2];
      float eb = Eb[(size_t)(q2*8 + 2*jp + 1)*NH + h2];
      unsigned ba = __float_as_uint(ea), bb = __float_as_uint(eb);
      float la = ea - __uint_as_float(ba & 0xFFFF0000u);
      float lb = eb - __uint_as_float(bb & 0xFFFF0000u);
      hi4[jp] = pack_bf16(ba, bb);
      lo4[jp] = pack_bf16(__float_as_uint(la), __float_as_uint(lb));
    }
    int off = h2*32 + ((q2 ^ ((h2>>1)&3))*8);
    *(uint4*)&ET[tbase + off]        = make_uint4(hi4[0],hi4[1],hi4[2],hi4[3]);
    *(uint4*)&ET[tbase + 6144 + off] = make_uint4(lo4[0],lo4[1],lo4[2],lo4[3]);
  }
}

// ---------------- Kernel B: Q/K projection + VQC evaluation ----------------
__global__ __launch_bounds__(256) void proj_vqc_kernel(
    const float* __restrict__ E, const float* __restrict__ Wq, const float* __restrict__ bq,
    const float* __restrict__ Wk, const float* __restrict__ bk,
    const float* __restrict__ Vre, const float* __restrict__ Vim,
    float* __restrict__ Qv, float* __restrict__ Kv) {
  __shared__ __align__(16) float WqL[768*4];
  __shared__ __align__(16) float WkL[768*4];
  __shared__ float Vsh[2][16*17];
  int tid = threadIdx.x;
  for (int idx = tid; idx < 768*4; idx += 256) {
    int e = idx >> 2, w = idx & 3;
    WqL[e*4+w] = Wq[w*768+e];
    WkL[e*4+w] = Wk[w*768+e];
  }
  if (tid < 256) {
    int i = tid >> 4, jj = tid & 15;
    Vsh[0][i*17+jj] = Vre[tid];
    Vsh[1][i*17+jj] = Vim[tid];
  }
  __syncthreads();
  float bqr0=bq[0], bqr1=bq[1], bqr2=bq[2], bqr3=bq[3];
  float bkr0=bk[0], bkr1=bk[1], bkr2=bk[2], bkr3=bk[3];
  int lane = tid & 63;
  int wid  = blockIdx.x*4 + (tid >> 6);
  int nw   = gridDim.x*4;
  int grp  = lane >> 4;
  int i    = lane & 15;
  for (int pos = wid; pos < NPOS; pos += nw) {
    const float* er = E + (size_t)pos*768;
    float pq[4] = {0.f,0.f,0.f,0.f};
    float pk[4] = {0.f,0.f,0.f,0.f};
#pragma unroll
    for (int k2 = 0; k2 < 3; k2++) {
      float4 ev = *(const float4*)(er + lane*4 + 256*k2);
#pragma unroll
      for (int jj = 0; jj < 4; jj++) {
        int e = lane*4 + 256*k2 + jj;
        float evs = (jj==0) ? ev.x : (jj==1) ? ev.y : (jj==2) ? ev.z : ev.w;
        float4 wq4 = *(const float4*)&WqL[e*4];
        float4 wk4 = *(const float4*)&WkL[e*4];
        pq[0] += evs*wq4.x; pq[1] += evs*wq4.y; pq[2] += evs*wq4.z; pq[3] += evs*wq4.w;
        pk[0] += evs*wk4.x; pk[1] += evs*wk4.y; pk[2] += evs*wk4.z; pk[3] += evs*wk4.w;
      }
    }
    float part[8];
#pragma unroll
    for (int w = 0; w < 8; w++) {
      float v = (w < 4) ? pq[w] : pk[w-4];
      v += __shfl_xor(v, 32); v += __shfl_xor(v, 16); v += __shfl_xor(v, 8);
      v += __shfl_xor(v, 4);  v += __shfl_xor(v, 2);  v += __shfl_xor(v, 1);
      part[w] = v;
    }
    if (grp < 2) {
      float a0,a1,a2,a3;
      if (grp == 0) { a0=part[0]+bqr0; a1=part[1]+bqr1; a2=part[2]+bqr2; a3=part[3]+bqr3; }
      else          { a0=part[4]+bkr0; a1=part[5]+bkr1; a2=part[6]+bkr2; a3=part[7]+bkr3; }
      float c0=cosf(0.5f*a0), s0=sinf(0.5f*a0);
      float c1=cosf(0.5f*a1), s1=sinf(0.5f*a1);
      float c2=cosf(0.5f*a2), s2=sinf(0.5f*a2);
      float c3=cosf(0.5f*a3), s3=sinf(0.5f*a3);
      float m[16];
#pragma unroll
      for (int j2 = 0; j2 < 16; j2++) {
        float f0 = (j2 & 8) ? s0 : c0;
        float f1 = (j2 & 4) ? s1 : c1;
        float f2 = (j2 & 2) ? s2 : c2;
        float f3 = (j2 & 1) ? s3 : c3;
        m[j2] = f0*f1*f2*f3;
      }
      float re = 0.f, im = 0.f;
#pragma unroll
      for (int j2 = 0; j2 < 16; j2++) {
        re += Vsh[0][i*17+j2]*m[j2];
        im += Vsh[1][i*17+j2]*m[j2];
      }
      float pr = re*re + im*im;
      float r0 = (i & 8) ? -pr : pr;
      float r1 = (i & 4) ? -pr : pr;
      float r2 = (i & 2) ? -pr : pr;
      float r3 = (i & 1) ? -pr : pr;
#pragma unroll
      for (int off = 8; off >= 1; off >>= 1) {
        r0 += __shfl_xor(r0, off);
        r1 += __shfl_xor(r1, off);
        r2 += __shfl_xor(r2, off);
        r3 += __shfl_xor(r3, off);
      }
      if (i == 0) {
        float* dst = (grp == 0 ? Qv : Kv) + (size_t)pos*4;
        dst[0]=r0; dst[1]=r1; dst[2]=r2; dst[3]=r3;
      }
    }
  }
}

// ---------------- Kernel C: fused flash attention, 128s x 192h, 8 waves ----------------
// RESTRUCTURED for P-gen/MFMA overlap:
//  - P for chunk k is computed during body k-1 and carried in REGISTERS (2x uint4);
//    it is committed to the single sA buffer in a tiny bar1->write->bar2 window at
//    the top of body k. So the heavy P-gen VALU work (dots/exp/split) of chunk k+1
//    runs in the same barrier-free region as the MFMAs of chunk k (separate pipes).
//  - kvf LDS buffer removed: Kv chunk rows are loaded straight into registers
//    (wave-uniform addresses, L1/L2-hit). kv loads are issued BEFORE the E-tile
//    global_load_lds so the compiler's wait is vmcnt(3) and the DMA stays in
//    flight across the whole body (drains at next bar1).
//  - LDS: sA 16 KB (single) + sB 2x24 KB + denp/dfin 2.5 KB = 66.5 KB -> 2 blocks/CU.
#define TKC 32

__global__ __launch_bounds__(512, 4) void attn_kernel(
    const unsigned short* __restrict__ ET, const float* __restrict__ Qv,
    const float* __restrict__ Kv, float* __restrict__ out) {
  int sblk = blockIdx.x;   // 0..15
  int hblk = blockIdx.y;   // 0..3
  int b    = blockIdx.z;   // 0..7
  int tid  = threadIdx.x;
  int lane = tid & 63;
  int w    = tid >> 6;     // 0..7

  __shared__ __align__(16) unsigned short sA[8192];       // hi [0,4096), lo [4096,8192)
  __shared__ __align__(16) unsigned short sB[2][12288];   // hi [0,6144), lo [6144,12288)
  __shared__ float denp[128*4];
  __shared__ float dfin[128];

  const unsigned short* tE = ET + ((size_t)((b*4 + hblk)*64)) * 12288;
  const float* Kvb = Kv + (size_t)b*NS*4;

  // P-gen mapping: s = tid&127, q-group = tid>>7 (wave-uniform)
  int sP = tid & 127, qP = tid >> 7;
  float4 qv = *(const float4*)&Qv[((size_t)(b*NS + sblk*128) + sP)*4];
  float den_acc = 0.f;
  int offA = sP*32 + ((qP ^ ((sP>>1)&3))*8);

  int sh = w & 1, hh = w >> 1;   // wave tile: 64 s x 48 h
  floatx4 acc[4][3];
#pragma unroll
  for (int i = 0; i < 4; i++)
#pragma unroll
    for (int jt = 0; jt < 3; jt++) acc[i][jt] = floatx4{0.f,0.f,0.f,0.f};

  int m16 = lane & 15, q16 = lane >> 4;
  int cidx = (q16 ^ ((m16 >> 1) & 3)) * 8;   // swizzled chunk offset for frag reads
  int t16 = tid * 8;                          // 16 B per thread per DMA round

  uint4 ph, pl;   // pending packed P (hi/lo) of the next chunk to be committed to sA

  auto kvload = [&](int tb, float4* kvr) {
    const float* kvp = Kvb + (size_t)(tb + qP*8)*4;
#pragma unroll
    for (int j = 0; j < 8; j++) kvr[j] = *(const float4*)(kvp + j*4);
  };

  auto pcompute = [&](const float4* kvr) {
    unsigned hi4[4], lo4[4];
    float dsum = 0.f;
#pragma unroll
    for (int jp = 0; jp < 4; jp++) {
      float4 ka = kvr[2*jp];
      float4 kb = kvr[2*jp+1];
      float arga = qv.x*ka.x + qv.y*ka.y + qv.z*ka.z + qv.w*ka.w;
      float argb = qv.x*kb.x + qv.y*kb.y + qv.z*kb.z + qv.w*kb.w;
      float pa = __expf(arga), pb = __expf(argb);
      dsum += pa + pb;
      unsigned bpa = __float_as_uint(pa), bpb = __float_as_uint(pb);
      float lpa = pa - __uint_as_float(bpa & 0xFFFF0000u);
      float lpb = pb - __uint_as_float(bpb & 0xFFFF0000u);
      hi4[jp] = pack_bf16(bpa, bpb);
      lo4[jp] = pack_bf16(__float_as_uint(lpa), __float_as_uint(lpb));
    }
    den_acc += dsum;
    ph = make_uint4(hi4[0],hi4[1],hi4[2],hi4[3]);
    pl = make_uint4(lo4[0],lo4[1],lo4[2],lo4[3]);
  };

  auto do_mfma = [&](const unsigned short* sBc) {
    short8 ah[4], al[4];
#pragma unroll
    for (int i = 0; i < 4; i++) {
      int srow = sh*64 + i*16 + m16;
      ah[i] = __builtin_bit_cast(short8, *(const uint4*)&sA[srow*TKC + cidx]);
      al[i] = __builtin_bit_cast(short8, *(const uint4*)&sA[4096 + srow*TKC + cidx]);
    }
#pragma unroll
    for (int jt = 0; jt < 3; jt++) {
      int hrow = hh*48 + jt*16 + m16;
      short8 bh_ = __builtin_bit_cast(short8, *(const uint4*)&sBc[hrow*TKC + cidx]);
      short8 bl_ = __builtin_bit_cast(short8, *(const uint4*)&sBc[6144 + hrow*TKC + cidx]);
#pragma unroll
      for (int i = 0; i < 4; i++) {
        acc[i][jt] = __builtin_amdgcn_mfma_f32_16x16x32_bf16(ah[i], bl_, acc[i][jt], 0, 0, 0);
        acc[i][jt] = __builtin_amdgcn_mfma_f32_16x16x32_bf16(al[i], bh_, acc[i][jt], 0, 0, 0);
        acc[i][jt] = __builtin_amdgcn_mfma_f32_16x16x32_bf16(ah[i], bh_, acc[i][jt], 0, 0, 0);
      }
    }
  };

  // ---- prologue: kv(0) loads, DMA E(0) -> sB[0], P-gen(0) -> (ph, pl) ----
  {
    float4 kvr[8];
    kvload(0, kvr);
    GLOAD_LDS16(tE + t16,        &sB[0][0] + t16);
    GLOAD_LDS16(tE + 4096 + t16, &sB[0][0] + 4096 + t16);
    GLOAD_LDS16(tE + 8192 + t16, &sB[0][0] + 8192 + t16);
    pcompute(kvr);
  }

  // ---- main loop: body k commits P(k), prefetches E(k+1)/kv(k+1),
  //      computes P(k+1) into regs overlapped with MFMA(k) ----
  for (int ci = 0; ci < 63; ci++) {
    int cb = ci & 1;

    __syncthreads();   // bar1: DMA(ci) drained; prev MFMA sA/sB reads retired
    *(uint4*)&sA[offA]        = ph;
    *(uint4*)&sA[4096 + offA] = pl;
    __syncthreads();   // bar2: P(ci) visible in sA

    float4 kvr[8];
    kvload((ci+1)*TKC, kvr);   // issued before DMA -> wait is vmcnt(3)

    const unsigned short* nE = tE + (size_t)(ci+1)*12288;
    unsigned short* sBn = &sB[cb^1][0];
    GLOAD_LDS16(nE + t16,        sBn + t16);
    GLOAD_LDS16(nE + 4096 + t16, sBn + 4096 + t16);
    GLOAD_LDS16(nE + 8192 + t16, sBn + 8192 + t16);

    pcompute(kvr);             // VALU/trans work overlaps the MFMAs below

    do_mfma(&sB[cb][0]);       // chunk ci
  }

  // ---- tail: chunk 63 ----
  __syncthreads();   // bar1: DMA(63) drained; MFMA(62) reads retired
  *(uint4*)&sA[offA]        = ph;
  *(uint4*)&sA[4096 + offA] = pl;
  __syncthreads();   // bar2
  do_mfma(&sB[1][0]);

  // --- denominator reduce ---
  denp[sP*4 + qP] = den_acc;
  __syncthreads();
  if (tid < 128) {
    dfin[tid] = denp[tid*4] + denp[tid*4+1] + denp[tid*4+2] + denp[tid*4+3];
  }
  __syncthreads();

  // --- epilogue: C/D layout col=lane&15, row=(lane>>4)*4+reg; scale by 1/den ---
  float* ob = out + ((size_t)(b*NS + sblk*128))*NH + hblk*192;
#pragma unroll
  for (int i = 0; i < 4; i++) {
#pragma unroll
    for (int reg = 0; reg < 4; reg++) {
      int row = q16*4 + reg;
      int s_loc = sh*64 + i*16 + row;
      float invd = 1.0f / dfin[s_loc];
#pragma unroll
      for (int jt = 0; jt < 3; jt++) {
        int h_loc = hh*48 + jt*16 + m16;
        ob[(size_t)s_loc*NH + h_loc] = acc[i][jt][reg] * invd;
      }
    }
  }
}

extern "C" void kernel_launch(void* const* d_in, const int* in_sizes, int n_in,
                              void* d_out, int out_size, void* d_ws, size_t ws_size,
                              hipStream_t stream) {
  const float* E   = (const float*)d_in[0];
  const float* Wq  = (const float*)d_in[1];
  const float* bq  = (const float*)d_in[2];
  const float* Wk  = (const float*)d_in[3];
  const float* bk  = (const float*)d_in[4];
  const float* wts = (const float*)d_in[5];
  float* ws  = (float*)d_ws;
  float* Vre = ws;                       // 256 f
  float* Vim = ws + 256;                 // 256 f
  float* Qv  = ws + 512;                 // NPOS*4 f
  float* Kv  = Qv + (size_t)NPOS*4;      // NPOS*4 f
  unsigned short* ET = (unsigned short*)(Kv + (size_t)NPOS*4);  // 50.3 MB
  float* out = (float*)d_out;

  epre_kernel<<<dim3(64, 4, 8), 384, 0, stream>>>(E, wts, Vre, Vim, ET);
  proj_vqc_kernel<<<1024, 256, 0, stream>>>(E, Wq, bq, Wk, bk, Vre, Vim, Qv, Kv);
  attn_kernel<<<dim3(16, 4, 8), 512, 0, stream>>>(ET, Qv, Kv, out);
}

// Round 2
// 258.830 us; speedup vs baseline: 1.1065x; 1.1065x over previous
//
#include <hip/hip_runtime.h>

#define NB 8
#define NS 2048
#define NH 768
#define NPOS (NB*NS)

typedef _Float16 half8 __attribute__((ext_vector_type(8)));
typedef float floatx4 __attribute__((ext_vector_type(4)));

// async global->LDS, 16B per lane; LDS dest must be wave-uniform base + lane*16
#define GLOAD_LDS16(gp, lp) __builtin_amdgcn_global_load_lds( \
  (const __attribute__((address_space(1))) unsigned int*)(gp), \
  (__attribute__((address_space(3))) unsigned int*)(lp), 16, 0, 0)

// ---------------- Kernel Epre: pre-tile E into swizzled f16 hi/lo tiles ----------------
// Tile (b, hb, tc) = [192 h][32 t], 12288 shorts (24 KB): hi image [0,6144),
// lo image [6144,12288); within each: off = h2*32 + ((q2^((h2>>1)&3))*8).
// f16 split: hi = f16(e) (RTN), lo = f16(e - hi) -> 22-bit effective mantissa.
// Block (0,0,0) threads 0..15 additionally build V = U*diag((-i)^popc) (tiny).
__global__ __launch_bounds__(384) void epre_kernel(
    const float* __restrict__ E, const float* __restrict__ wts,
    float* __restrict__ Vre, float* __restrict__ Vim,
    unsigned short* __restrict__ ET) {
  int tc = blockIdx.x, hb = blockIdx.y, b = blockIdx.z;
  int tid = threadIdx.x;

  if (tc == 0 && hb == 0 && b == 0 && tid < 16) {
    int j = tid;
    float ar[16], ai[16];
#pragma unroll
    for (int i = 0; i < 16; i++) { ar[i] = (i == j) ? 1.f : 0.f; ai[i] = 0.f; }
#pragma unroll
    for (int l = 0; l < 2; l++) {
#pragma unroll
      for (int q = 0; q < 4; q++) {
        float phi = wts[(l*4+q)*3+0];
        float th  = wts[(l*4+q)*3+1];
        float om  = wts[(l*4+q)*3+2];
        float ct = cosf(0.5f*th), st = sinf(0.5f*th);
        float sm = 0.5f*(phi+om), df = 0.5f*(phi-om);
        float cs = cosf(sm), ss = sinf(sm), cd = cosf(df), sd = sinf(df);
        float Ar =  cs*ct, Ai = -ss*ct;
        float Br = -cd*st, Bi = -sd*st;
        float Cr =  cd*st, Ci = -sd*st;
        float Dr =  cs*ct, Di =  ss*ct;
        int pb = 1 << (3-q);
#pragma unroll
        for (int b0 = 0; b0 < 16; b0++) {
          if (b0 & pb) continue;
          int b1 = b0 | pb;
          float xr = ar[b0], xi = ai[b0], yr = ar[b1], yi = ai[b1];
          ar[b0] = Ar*xr - Ai*xi + Br*yr - Bi*yi;
          ai[b0] = Ar*xi + Ai*xr + Br*yi + Bi*yr;
          ar[b1] = Cr*xr - Ci*xi + Dr*yr - Di*yi;
          ai[b1] = Cr*xi + Ci*xr + Dr*yi + Di*yr;
        }
      }
      const int r = (l == 0) ? 1 : 2;
#pragma unroll
      for (int i2 = 0; i2 < 4; i2++) {
        int cb = 1 << (3-i2);
        int tb = 1 << (3-((i2+r)&3));
#pragma unroll
        for (int b0 = 0; b0 < 16; b0++) {
          if ((b0 & cb) && !(b0 & tb)) {
            int b1 = b0 | tb;
            float tr = ar[b0], ti = ai[b0];
            ar[b0] = ar[b1]; ai[b0] = ai[b1];
            ar[b1] = tr;     ai[b1] = ti;
          }
        }
      }
    }
    int pc = __popc((unsigned)j) & 3;
#pragma unroll
    for (int i = 0; i < 16; i++) {
      float vr = ar[i], vi = ai[i], orr, oi;
      if      (pc == 0) { orr =  vr; oi =  vi; }
      else if (pc == 1) { orr =  vi; oi = -vr; }
      else if (pc == 2) { orr = -vr; oi = -vi; }
      else              { orr = -vi; oi =  vr; }
      Vre[i*16+j] = orr;
      Vim[i*16+j] = oi;
    }
  }

  size_t tbase = ((size_t)((b*4 + hb)*64 + tc)) * 12288;
  const float* Eb = E + (size_t)b*NS*NH + (size_t)tc*32*NH + hb*192;
#pragma unroll
  for (int u = 0; u < 2; u++) {
    int unit = tid + 384*u;          // 0..767
    int q2 = unit / 192, h2 = unit % 192;
    unsigned hi4[4], lo4[4];
#pragma unroll
    for (int jp = 0; jp < 4; jp++) {
      float ea = Eb[(size_t)(q2*8 + 2*jp    )*NH + h2];
      float eb = Eb[(size_t)(q2*8 + 2*jp + 1)*NH + h2];
      _Float16 ha = (_Float16)ea, hb16 = (_Float16)eb;
      float la = ea - (float)ha, lb = eb - (float)hb16;
      unsigned uha = __builtin_bit_cast(unsigned short, ha);
      unsigned uhb = __builtin_bit_cast(unsigned short, hb16);
      unsigned ula = __builtin_bit_cast(unsigned short, (_Float16)la);
      unsigned ulb = __builtin_bit_cast(unsigned short, (_Float16)lb);
      hi4[jp] = uha | (uhb << 16);
      lo4[jp] = ula | (ulb << 16);
    }
    int off = h2*32 + ((q2 ^ ((h2>>1)&3))*8);
    *(uint4*)&ET[tbase + off]        = make_uint4(hi4[0],hi4[1],hi4[2],hi4[3]);
    *(uint4*)&ET[tbase + 6144 + off] = make_uint4(lo4[0],lo4[1],lo4[2],lo4[3]);
  }
}

// ---------------- Kernel B: Q/K projection + VQC evaluation ----------------
__global__ __launch_bounds__(256) void proj_vqc_kernel(
    const float* __restrict__ E, const float* __restrict__ Wq, const float* __restrict__ bq,
    const float* __restrict__ Wk, const float* __restrict__ bk,
    const float* __restrict__ Vre, const float* __restrict__ Vim,
    float* __restrict__ Qv, float* __restrict__ Kv) {
  __shared__ __align__(16) float WqL[768*4];
  __shared__ __align__(16) float WkL[768*4];
  __shared__ float Vsh[2][16*17];
  int tid = threadIdx.x;
  for (int idx = tid; idx < 768*4; idx += 256) {
    int e = idx >> 2, w = idx & 3;
    WqL[e*4+w] = Wq[w*768+e];
    WkL[e*4+w] = Wk[w*768+e];
  }
  if (tid < 256) {
    int i = tid >> 4, jj = tid & 15;
    Vsh[0][i*17+jj] = Vre[tid];
    Vsh[1][i*17+jj] = Vim[tid];
  }
  __syncthreads();
  float bqr0=bq[0], bqr1=bq[1], bqr2=bq[2], bqr3=bq[3];
  float bkr0=bk[0], bkr1=bk[1], bkr2=bk[2], bkr3=bk[3];
  int lane = tid & 63;
  int wid  = blockIdx.x*4 + (tid >> 6);
  int nw   = gridDim.x*4;
  int grp  = lane >> 4;
  int i    = lane & 15;
  for (int pos = wid; pos < NPOS; pos += nw) {
    const float* er = E + (size_t)pos*768;
    float pq[4] = {0.f,0.f,0.f,0.f};
    float pk[4] = {0.f,0.f,0.f,0.f};
#pragma unroll
    for (int k2 = 0; k2 < 3; k2++) {
      float4 ev = *(const float4*)(er + lane*4 + 256*k2);
#pragma unroll
      for (int jj = 0; jj < 4; jj++) {
        int e = lane*4 + 256*k2 + jj;
        float evs = (jj==0) ? ev.x : (jj==1) ? ev.y : (jj==2) ? ev.z : ev.w;
        float4 wq4 = *(const float4*)&WqL[e*4];
        float4 wk4 = *(const float4*)&WkL[e*4];
        pq[0] += evs*wq4.x; pq[1] += evs*wq4.y; pq[2] += evs*wq4.z; pq[3] += evs*wq4.w;
        pk[0] += evs*wk4.x; pk[1] += evs*wk4.y; pk[2] += evs*wk4.z; pk[3] += evs*wk4.w;
      }
    }
    float part[8];
#pragma unroll
    for (int w = 0; w < 8; w++) {
      float v = (w < 4) ? pq[w] : pk[w-4];
      v += __shfl_xor(v, 32); v += __shfl_xor(v, 16); v += __shfl_xor(v, 8);
      v += __shfl_xor(v, 4);  v += __shfl_xor(v, 2);  v += __shfl_xor(v, 1);
      part[w] = v;
    }
    if (grp < 2) {
      float a0,a1,a2,a3;
      if (grp == 0) { a0=part[0]+bqr0; a1=part[1]+bqr1; a2=part[2]+bqr2; a3=part[3]+bqr3; }
      else          { a0=part[4]+bkr0; a1=part[5]+bkr1; a2=part[6]+bkr2; a3=part[7]+bkr3; }
      float c0=cosf(0.5f*a0), s0=sinf(0.5f*a0);
      float c1=cosf(0.5f*a1), s1=sinf(0.5f*a1);
      float c2=cosf(0.5f*a2), s2=sinf(0.5f*a2);
      float c3=cosf(0.5f*a3), s3=sinf(0.5f*a3);
      float m[16];
#pragma unroll
      for (int j2 = 0; j2 < 16; j2++) {
        float f0 = (j2 & 8) ? s0 : c0;
        float f1 = (j2 & 4) ? s1 : c1;
        float f2 = (j2 & 2) ? s2 : c2;
        float f3 = (j2 & 1) ? s3 : c3;
        m[j2] = f0*f1*f2*f3;
      }
      float re = 0.f, im = 0.f;
#pragma unroll
      for (int j2 = 0; j2 < 16; j2++) {
        re += Vsh[0][i*17+j2]*m[j2];
        im += Vsh[1][i*17+j2]*m[j2];
      }
      float pr = re*re + im*im;
      float r0 = (i & 8) ? -pr : pr;
      float r1 = (i & 4) ? -pr : pr;
      float r2 = (i & 2) ? -pr : pr;
      float r3 = (i & 1) ? -pr : pr;
#pragma unroll
      for (int off = 8; off >= 1; off >>= 1) {
        r0 += __shfl_xor(r0, off);
        r1 += __shfl_xor(r1, off);
        r2 += __shfl_xor(r2, off);
        r3 += __shfl_xor(r3, off);
      }
      if (i == 0) {
        float* dst = (grp == 0 ? Qv : Kv) + (size_t)pos*4;
        dst[0]=r0; dst[1]=r1; dst[2]=r2; dst[3]=r3;
      }
    }
  }
}

// ---------------- Kernel C: fused flash attention, 128s x 192h, 8 waves ----------------
// f16 2-pass scheme (was bf16 3-pass):
//  - E in f16 hi + f16 lo (22-bit effective) in sB, double-buffered.
//  - P = exp(q.k) in SINGLE f16 image (P in (0.018, 54.6), f16 RTN rel err 2^-12);
//    denominator still accumulated from exact fp32 exp.
//  - MFMA per wave per chunk: 24 (was 36); ds_read_b128: 10 (was 14).
//  - sA double-buffered in the freed space -> ONE barrier per chunk (was 2):
//    body ci reads sA[cb]/sB[cb], prefetches kv/E(ci+1) and writes P(ci+1)
//    into sA[nb]; single __syncthreads at body top orders everything.
//  - LDS: sA 2x8KB + sB 2x24KB + denp/dfin 2.5KB = 66.5 KB -> 2 blocks/CU.
#define TKC 32

__global__ __launch_bounds__(512, 4) void attn_kernel(
    const unsigned short* __restrict__ ET, const float* __restrict__ Qv,
    const float* __restrict__ Kv, float* __restrict__ out) {
  int sblk = blockIdx.x;   // 0..15
  int hblk = blockIdx.y;   // 0..3
  int b    = blockIdx.z;   // 0..7
  int tid  = threadIdx.x;
  int lane = tid & 63;
  int w    = tid >> 6;     // 0..7

  __shared__ __align__(16) unsigned short sA[2][4096];    // f16 P, double-buffered
  __shared__ __align__(16) unsigned short sB[2][12288];   // hi [0,6144), lo [6144,12288)
  __shared__ float denp[128*4];
  __shared__ float dfin[128];

  const unsigned short* tE = ET + ((size_t)((b*4 + hblk)*64)) * 12288;
  const float* Kvb = Kv + (size_t)b*NS*4;

  // P-gen mapping: s = tid&127, q-group = tid>>7 (wave-uniform)
  int sP = tid & 127, qP = tid >> 7;
  float4 qv = *(const float4*)&Qv[((size_t)(b*NS + sblk*128) + sP)*4];
  float den_acc = 0.f;
  int offA = sP*32 + ((qP ^ ((sP>>1)&3))*8);

  int sh = w & 1, hh = w >> 1;   // wave tile: 64 s x 48 h
  floatx4 acc[4][3];
#pragma unroll
  for (int i = 0; i < 4; i++)
#pragma unroll
    for (int jt = 0; jt < 3; jt++) acc[i][jt] = floatx4{0.f,0.f,0.f,0.f};

  int m16 = lane & 15, q16 = lane >> 4;
  int cidx = (q16 ^ ((m16 >> 1) & 3)) * 8;   // swizzled chunk offset for frag reads
  int t16 = tid * 8;                          // 16 B per thread per DMA round

  auto kvload = [&](int tb, float4* kvr) {
    const float* kvp = Kvb + (size_t)(tb + qP*8)*4;
#pragma unroll
    for (int j = 0; j < 8; j++) kvr[j] = *(const float4*)(kvp + j*4);
  };

  // compute 8 P values for (sP, t = qP*8 + j), pack as f16 pairs
  auto pcompute = [&](const float4* kvr) -> uint4 {
    unsigned h4[4];
    float dsum = 0.f;
#pragma unroll
    for (int jp = 0; jp < 4; jp++) {
      float4 ka = kvr[2*jp];
      float4 kb = kvr[2*jp+1];
      float arga = qv.x*ka.x + qv.y*ka.y + qv.z*ka.z + qv.w*ka.w;
      float argb = qv.x*kb.x + qv.y*kb.y + qv.z*kb.z + qv.w*kb.w;
      float pa = __expf(arga), pb = __expf(argb);
      dsum += pa + pb;
      unsigned ua = (unsigned)__builtin_bit_cast(unsigned short, (_Float16)pa);
      unsigned ub = (unsigned)__builtin_bit_cast(unsigned short, (_Float16)pb);
      h4[jp] = ua | (ub << 16);
    }
    den_acc += dsum;
    return make_uint4(h4[0], h4[1], h4[2], h4[3]);
  };

  auto do_mfma = [&](const unsigned short* sAc, const unsigned short* sBc) {
    half8 a[4];
#pragma unroll
    for (int i = 0; i < 4; i++) {
      int srow = sh*64 + i*16 + m16;
      a[i] = __builtin_bit_cast(half8, *(const uint4*)&sAc[srow*TKC + cidx]);
    }
#pragma unroll
    for (int jt = 0; jt < 3; jt++) {
      int hrow = hh*48 + jt*16 + m16;
      half8 bh_ = __builtin_bit_cast(half8, *(const uint4*)&sBc[hrow*TKC + cidx]);
      half8 bl_ = __builtin_bit_cast(half8, *(const uint4*)&sBc[6144 + hrow*TKC + cidx]);
#pragma unroll
      for (int i = 0; i < 4; i++) {
        acc[i][jt] = __builtin_amdgcn_mfma_f32_16x16x32_f16(a[i], bl_, acc[i][jt], 0, 0, 0);
        acc[i][jt] = __builtin_amdgcn_mfma_f32_16x16x32_f16(a[i], bh_, acc[i][jt], 0, 0, 0);
      }
    }
  };

  // ---- prologue: kv(0) loads, DMA E(0) -> sB[0], P(0) -> sA[0] ----
  {
    float4 kvr[8];
    kvload(0, kvr);
    GLOAD_LDS16(tE + t16,        &sB[0][0] + t16);
    GLOAD_LDS16(tE + 4096 + t16, &sB[0][0] + 4096 + t16);
    GLOAD_LDS16(tE + 8192 + t16, &sB[0][0] + 8192 + t16);
    uint4 ph = pcompute(kvr);
    *(uint4*)&sA[0][offA] = ph;
  }

  // ---- main loop: ONE barrier per chunk. Body ci: barrier (sA[cb]/sB[cb]
  //      ready, prev reads retired), prefetch chunk ci+1 into the nb buffers,
  //      then MFMA chunk ci. ----
  for (int ci = 0; ci < 64; ci++) {
    int cb = ci & 1;
    __syncthreads();
    if (ci < 63) {
      float4 kvr[8];
      kvload((ci+1)*TKC, kvr);
      const unsigned short* nE = tE + (size_t)(ci+1)*12288;
      unsigned short* sBn = &sB[cb^1][0];
      GLOAD_LDS16(nE + t16,        sBn + t16);
      GLOAD_LDS16(nE + 4096 + t16, sBn + 4096 + t16);
      GLOAD_LDS16(nE + 8192 + t16, sBn + 8192 + t16);
      uint4 ph = pcompute(kvr);
      *(uint4*)&sA[cb^1][offA] = ph;
    }
    do_mfma(&sA[cb][0], &sB[cb][0]);
  }

  // --- denominator reduce ---
  __syncthreads();
  denp[sP*4 + qP] = den_acc;
  __syncthreads();
  if (tid < 128) {
    dfin[tid] = denp[tid*4] + denp[tid*4+1] + denp[tid*4+2] + denp[tid*4+3];
  }
  __syncthreads();

  // --- epilogue: C/D layout col=lane&15, row=(lane>>4)*4+reg; scale by 1/den ---
  float* ob = out + ((size_t)(b*NS + sblk*128))*NH + hblk*192;
#pragma unroll
  for (int i = 0; i < 4; i++) {
#pragma unroll
    for (int reg = 0; reg < 4; reg++) {
      int row = q16*4 + reg;
      int s_loc = sh*64 + i*16 + row;
      float invd = 1.0f / dfin[s_loc];
#pragma unroll
      for (int jt = 0; jt < 3; jt++) {
        int h_loc = hh*48 + jt*16 + m16;
        ob[(size_t)s_loc*NH + h_loc] = acc[i][jt][reg] * invd;
      }
    }
  }
}

extern "C" void kernel_launch(void* const* d_in, const int* in_sizes, int n_in,
                              void* d_out, int out_size, void* d_ws, size_t ws_size,
                              hipStream_t stream) {
  const float* E   = (const float*)d_in[0];
  const float* Wq  = (const float*)d_in[1];
  const float* bq  = (const float*)d_in[2];
  const float* Wk  = (const float*)d_in[3];
  const float* bk  = (const float*)d_in[4];
  const float* wts = (const float*)d_in[5];
  float* ws  = (float*)d_ws;
  float* Vre = ws;                       // 256 f
  float* Vim = ws + 256;                 // 256 f
  float* Qv  = ws + 512;                 // NPOS*4 f
  float* Kv  = Qv + (size_t)NPOS*4;      // NPOS*4 f
  unsigned short* ET = (unsigned short*)(Kv + (size_t)NPOS*4);  // 50.3 MB
  float* out = (float*)d_out;

  epre_kernel<<<dim3(64, 4, 8), 384, 0, stream>>>(E, wts, Vre, Vim, ET);
  proj_vqc_kernel<<<1024, 256, 0, stream>>>(E, Wq, bq, Wk, bk, Vre, Vim, Qv, Kv);
  attn_kernel<<<dim3(16, 4, 8), 512, 0, stream>>>(ET, Qv, Kv, out);
}